// Round 5
// baseline (225.820 us; speedup 1.0000x reference)
//
#include <hip/hip_runtime.h>
#include <hip/hip_bf16.h>

#define LL 320
#define CC 128
#define HH 4
#define DD 32
#define MM (LL*LL)

typedef float f32x4 __attribute__((ext_vector_type(4)));
typedef short bf16x8 __attribute__((ext_vector_type(8)));

static __device__ __forceinline__ unsigned short f2b(float f) {
    union { float f; unsigned u; } v; v.f = f;
    unsigned r = (v.u + 0x7fffu + ((v.u >> 16) & 1u)) >> 16;
    return (unsigned short)r;
}
static __device__ __forceinline__ float b2f(unsigned short b) {
    union { unsigned u; float f; } v; v.u = ((unsigned)b) << 16;
    return v.f;
}

// ---------------------------------------------------------------- weights
// WT[mat][n][k] bf16, mat order: 0=q 1=k 2=v 3=g 4=o
__global__ void wtr_kernel(const float* __restrict__ W0, const float* __restrict__ W1,
                           const float* __restrict__ W2, const float* __restrict__ W3,
                           const float* __restrict__ W4, unsigned short* __restrict__ WT)
{
    int mat = blockIdx.x;
    const float* W = (mat == 0) ? W0 : (mat == 1) ? W1 : (mat == 2) ? W2 : (mat == 3) ? W3 : W4;
    unsigned short* dst = WT + (size_t)mat * CC * CC;
    for (int e = threadIdx.x; e < CC * CC; e += blockDim.x) {
        int n = e >> 7, k = e & 127;
        dst[n * CC + k] = f2b(W[k * CC + n]);
    }
}

// ---------------------------------------------------------------- QKVG projection
// A tile 64x128 bf16 (swizzled) staged once; loop over 4 weight mats.
__launch_bounds__(256)
__global__ void proj_kernel(const float* __restrict__ X, const unsigned short* __restrict__ WT,
                            const float* __restrict__ bq, const float* __restrict__ bk,
                            const float* __restrict__ bv, const float* __restrict__ bg,
                            unsigned short* __restrict__ qb, unsigned short* __restrict__ kb,
                            unsigned short* __restrict__ vb, unsigned short* __restrict__ gb)
{
    __shared__ unsigned char lds[16384 + 32768];
    const int t = threadIdx.x;
    const int m0 = blockIdx.x * 64;

    // stage A: 64 rows x 128 k, fp32 -> bf16, row stride 256B, slot-XOR swizzle
#pragma unroll
    for (int it = 0; it < 8; ++it) {
        int idx = t + it * 256;              // 0..2047 float4 chunks
        int row = idx >> 5, c4 = idx & 31;
        float4 f = *(const float4*)(X + (size_t)(m0 + row) * CC + c4 * 4);
        unsigned off = (unsigned)(row * 256) + (((unsigned)(c4 * 8)) ^ (((unsigned)(row & 7)) << 4));
        unsigned* p = (unsigned*)(lds + off);
        p[0] = (unsigned)f2b(f.x) | ((unsigned)f2b(f.y) << 16);
        p[1] = (unsigned)f2b(f.z) | ((unsigned)f2b(f.w) << 16);
    }

    const int lane = t & 63, w = t >> 6;
    const int lr = lane & 15, g = lane >> 4;
    const int wr = w >> 1, wc = w & 1;

#pragma unroll
    for (int mat = 0; mat < 4; ++mat) {
        __syncthreads();   // prev compute done (and A visible on iter 0)
        const unsigned short* wsrc = WT + (size_t)mat * CC * CC;
#pragma unroll
        for (int it = 0; it < 8; ++it) {
            int idx = t + it * 256;          // 0..2047 16B chunks (128 rows x 256B)
            int row = idx >> 4, c = idx & 15;
            uint4 d = *(const uint4*)(wsrc + row * CC + c * 8);
            *(uint4*)(lds + 16384 + row * 256u + (((unsigned)(c * 16)) ^ (((unsigned)(row & 7)) << 4))) = d;
        }
        __syncthreads();

        f32x4 acc[2][4] = {};
#pragma unroll
        for (int kk = 0; kk < 4; ++kk) {
            bf16x8 a[2], b[4];
#pragma unroll
            for (int m = 0; m < 2; ++m) {
                int row = wr * 32 + m * 16 + lr;
                a[m] = *(const bf16x8*)(lds + row * 256u +
                        (((unsigned)(kk * 64 + g * 16)) ^ (((unsigned)(row & 7)) << 4)));
            }
#pragma unroll
            for (int n = 0; n < 4; ++n) {
                int row = wc * 64 + n * 16 + lr;
                b[n] = *(const bf16x8*)(lds + 16384 + row * 256u +
                        (((unsigned)(kk * 64 + g * 16)) ^ (((unsigned)(row & 7)) << 4)));
            }
#pragma unroll
            for (int m = 0; m < 2; ++m)
#pragma unroll
                for (int n = 0; n < 4; ++n)
                    acc[m][n] = __builtin_amdgcn_mfma_f32_16x16x32_bf16(a[m], b[n], acc[m][n], 0, 0, 0);
        }

        const float* bias = (mat == 0) ? bq : (mat == 1) ? bk : (mat == 2) ? bv : bg;
        unsigned short* op = (mat == 0) ? qb : (mat == 1) ? kb : (mat == 2) ? vb : gb;
#pragma unroll
        for (int m = 0; m < 2; ++m)
#pragma unroll
            for (int n = 0; n < 4; ++n) {
                int col = wc * 64 + n * 16 + lr;
                float bs = bias[col];
#pragma unroll
                for (int r = 0; r < 4; ++r) {
                    int row = m0 + wr * 32 + m * 16 + g * 4 + r;
                    float v = acc[m][n][r] + bs;
                    if (mat == 3) v = 1.0f / (1.0f + __expf(-v));
                    op[(size_t)row * CC + col] = f2b(v);
                }
            }
    }
}

// ---------------------------------------------------------------- attention
// One block per (i,h). 4 waves x 80 q-rows. Swapped S^T = mfma(K,Q), per-lane
// softmax denominator (no max subtraction: scores bounded), O^T = mfma(V^T,P).
// P round-trip ELIMINATED via k-permutation k=g*8+u <-> j=(u>>2)*16+g*4+(u&3):
// applied identically to the V^T (A) and P (B) operands, so the contraction is
// a j-bijection for ANY hardware lane->k mapping (robust; round-3-verified
// facts only: A-row=lane&15, B-col=lane&15, kappa_A==kappa_B, D-layout).
// NOTE: output buffer ab MAY alias qb: each block reads Q only from its own
// disjoint (i,h) region into registers before writing O to that same region.
__launch_bounds__(256)
__global__ void attn_kernel(const unsigned short* __restrict__ qb, const unsigned short* __restrict__ kb,
                            const unsigned short* __restrict__ vb, unsigned short* __restrict__ ab)
{
    __shared__ unsigned char lds[20480 + 20480];
    // [0,20480): K [320][32] bf16, row stride 64B, slot ^= (j&3)
    // [20480,40960): VT [32][320] bf16, row stride 640B, slot ^= (d&7)
    const int i = blockIdx.x, h = blockIdx.y;
    const int t = threadIdx.x;
    const size_t base = ((size_t)i * LL) * CC + h * DD;

#pragma unroll
    for (int it = 0; it < 5; ++it) {              // K: 320 rows x 64B
        int idx = t + it * 256;                   // 0..1279
        int j = idx >> 2, ch = idx & 3;
        uint4 d = *(const uint4*)(kb + base + (size_t)j * CC + ch * 8);
        *(uint4*)(lds + j * 64u + ((unsigned)(ch ^ (j & 3)) << 4)) = d;
    }
#pragma unroll
    for (int it = 0; it < 5; ++it) {              // V -> VT transpose
        int idx = t + it * 256;
        int j = idx >> 2, ch = idx & 3;
        uint4 d = *(const uint4*)(vb + base + (size_t)j * CC + ch * 8);
        const unsigned short* ev = (const unsigned short*)&d;
#pragma unroll
        for (int u = 0; u < 8; ++u) {
            int dd = ch * 8 + u;
            unsigned off = 20480u + dd * 640u + (((unsigned)((j >> 3) ^ (dd & 7))) << 4) + (j & 7) * 2;
            *(unsigned short*)(lds + off) = ev[u];
        }
    }

    const int lane = t & 63, w = t >> 6;
    const int lr = lane & 15, g = lane >> 4;

    bf16x8 qf[5];                                  // B=Q fragments, loaded once
#pragma unroll
    for (int f = 0; f < 5; ++f) {
        int q = w * 80 + f * 16 + lr;
        qf[f] = *(const bf16x8*)(qb + base + (size_t)q * CC + g * 8);
    }
    __syncthreads();

    f32x4 acc[5][2] = {};                          // O^T: [qfrag][dfrag]; col=q(lr), row=d
    float lsum[5] = {};
    const float sc = 0.25506601f;                  // log2(e)/sqrt(32)
    f32x4 zero = {0.f, 0.f, 0.f, 0.f};

    for (int c = 0; c < 10; ++c) {                 // j-chunks of 32
        bf16x8 kf[2];
#pragma unroll
        for (int tt = 0; tt < 2; ++tt) {
            int j = c * 32 + tt * 16 + lr;
            kf[tt] = *(const bf16x8*)(lds + j * 64u + ((unsigned)(g ^ (j & 3)) << 4));
        }
        // A=V^T fragments in permuted-j order: elem u=0..3 -> j=c*32+g*4+u,
        // u=4..7 -> j=c*32+16+g*4+(u-4); row d = df*16+lr. Two 8B reads.
        union { bf16x8 v; uint2 u2[2]; } vfrag[2];
#pragma unroll
        for (int df = 0; df < 2; ++df) {
            int dd = df * 16 + lr;
            unsigned rowb = 20480u + dd * 640u + (unsigned)(g & 1) * 8;
            unsigned s0 = (unsigned)((c * 4 + (g >> 1)) ^ (dd & 7));
            unsigned s1 = (unsigned)((c * 4 + (g >> 1) + 2) ^ (dd & 7));
            vfrag[df].u2[0] = *(const uint2*)(lds + rowb + (s0 << 4));
            vfrag[df].u2[1] = *(const uint2*)(lds + rowb + (s1 << 4));
        }
#pragma unroll
        for (int f = 0; f < 5; ++f) {
            f32x4 s0 = __builtin_amdgcn_mfma_f32_16x16x32_bf16(kf[0], qf[f], zero, 0, 0, 0);
            f32x4 s1 = __builtin_amdgcn_mfma_f32_16x16x32_bf16(kf[1], qf[f], zero, 0, 0, 0);
            float p0 = exp2f(s0[0] * sc), p1 = exp2f(s0[1] * sc);
            float p2 = exp2f(s0[2] * sc), p3 = exp2f(s0[3] * sc);
            float p4 = exp2f(s1[0] * sc), p5 = exp2f(s1[1] * sc);
            float p6 = exp2f(s1[2] * sc), p7 = exp2f(s1[3] * sc);
            lsum[f] += ((p0 + p1) + (p2 + p3)) + ((p4 + p5) + (p6 + p7));
            // B=P fragment built in-register: elem u order matches vfrag's
            // permuted-j order (s0 regs r -> j=g*4+r, s1 regs r -> j=16+g*4+r)
            union { bf16x8 v; unsigned u[4]; } pf;
            pf.u[0] = (unsigned)f2b(p0) | ((unsigned)f2b(p1) << 16);
            pf.u[1] = (unsigned)f2b(p2) | ((unsigned)f2b(p3) << 16);
            pf.u[2] = (unsigned)f2b(p4) | ((unsigned)f2b(p5) << 16);
            pf.u[3] = (unsigned)f2b(p6) | ((unsigned)f2b(p7) << 16);
            acc[f][0] = __builtin_amdgcn_mfma_f32_16x16x32_bf16(vfrag[0].v, pf.v, acc[f][0], 0, 0, 0);
            acc[f][1] = __builtin_amdgcn_mfma_f32_16x16x32_bf16(vfrag[1].v, pf.v, acc[f][1], 0, 0, 0);
        }
    }

#pragma unroll
    for (int f = 0; f < 5; ++f) {
        float l = lsum[f];
        l += __shfl_xor(l, 16);
        l += __shfl_xor(l, 32);
        float inv = 1.0f / l;
        int q = w * 80 + f * 16 + lr;
        size_t orow = base + (size_t)q * CC;
#pragma unroll
        for (int df = 0; df < 2; ++df) {
            unsigned o0 = (unsigned)f2b(acc[f][df][0] * inv) | ((unsigned)f2b(acc[f][df][1] * inv) << 16);
            unsigned o1 = (unsigned)f2b(acc[f][df][2] * inv) | ((unsigned)f2b(acc[f][df][3] * inv) << 16);
            uint2 ov = {o0, o1};
            *(uint2*)(ab + orow + df * 16 + g * 4) = ov;
        }
    }
}

// ---------------------------------------------------------------- O-proj + gate
__launch_bounds__(256)
__global__ void out_kernel(const unsigned short* __restrict__ ab, const unsigned short* __restrict__ WT,
                           const float* __restrict__ bo, const unsigned short* __restrict__ gb,
                           float* __restrict__ out)
{
    __shared__ unsigned char lds[16384 + 32768];
    const int t = threadIdx.x;
    const int m0 = blockIdx.x * 64;
#pragma unroll
    for (int it = 0; it < 4; ++it) {               // A: 64 rows x 256B bf16
        int idx = t + it * 256;                    // 0..1023
        int row = idx >> 4, c = idx & 15;
        uint4 d = *(const uint4*)(ab + (size_t)(m0 + row) * CC + c * 8);
        *(uint4*)(lds + row * 256u + (((unsigned)(c * 16)) ^ (((unsigned)(row & 7)) << 4))) = d;
    }
    const unsigned short* wsrc = WT + (size_t)4 * CC * CC;
#pragma unroll
    for (int it = 0; it < 8; ++it) {               // B: 128 rows x 256B
        int idx = t + it * 256;
        int row = idx >> 4, c = idx & 15;
        uint4 d = *(const uint4*)(wsrc + row * CC + c * 8);
        *(uint4*)(lds + 16384 + row * 256u + (((unsigned)(c * 16)) ^ (((unsigned)(row & 7)) << 4))) = d;
    }
    __syncthreads();

    const int lane = t & 63, w = t >> 6;
    const int lr = lane & 15, g = lane >> 4;
    const int wr = w >> 1, wc = w & 1;
    f32x4 acc[2][4] = {};
#pragma unroll
    for (int kk = 0; kk < 4; ++kk) {
        bf16x8 a[2], b[4];
#pragma unroll
        for (int m = 0; m < 2; ++m) {
            int row = wr * 32 + m * 16 + lr;
            a[m] = *(const bf16x8*)(lds + row * 256u +
                    (((unsigned)(kk * 64 + g * 16)) ^ (((unsigned)(row & 7)) << 4)));
        }
#pragma unroll
        for (int n = 0; n < 4; ++n) {
            int row = wc * 64 + n * 16 + lr;
            b[n] = *(const bf16x8*)(lds + 16384 + row * 256u +
                    (((unsigned)(kk * 64 + g * 16)) ^ (((unsigned)(row & 7)) << 4)));
        }
#pragma unroll
        for (int m = 0; m < 2; ++m)
#pragma unroll
            for (int n = 0; n < 4; ++n)
                acc[m][n] = __builtin_amdgcn_mfma_f32_16x16x32_bf16(a[m], b[n], acc[m][n], 0, 0, 0);
    }
#pragma unroll
    for (int m = 0; m < 2; ++m)
#pragma unroll
        for (int n = 0; n < 4; ++n) {
            int col = wc * 64 + n * 16 + lr;
            float bs = bo[col];
#pragma unroll
            for (int r = 0; r < 4; ++r) {
                int row = m0 + wr * 32 + m * 16 + g * 4 + r;
                float y = acc[m][n][r] + bs;
                float gt = b2f(gb[(size_t)row * CC + col]);
                out[(size_t)row * CC + col] = y * gt;
            }
        }
}

// ---------------------------------------------------------------- launch
extern "C" void kernel_launch(void* const* d_in, const int* in_sizes, int n_in,
                              void* d_out, int out_size, void* d_ws, size_t ws_size,
                              hipStream_t stream)
{
    const float* pair = (const float*)d_in[0];
    const float* Wq = (const float*)d_in[1];  const float* bq = (const float*)d_in[2];
    const float* Wk = (const float*)d_in[3];  const float* bk = (const float*)d_in[4];
    const float* Wv = (const float*)d_in[5];  const float* bv = (const float*)d_in[6];
    const float* Wo = (const float*)d_in[7];  const float* bo = (const float*)d_in[8];
    const float* Wg = (const float*)d_in[9];  const float* bg = (const float*)d_in[10];

    char* ws = (char*)d_ws;
    unsigned short* WT = (unsigned short*)ws;                 // 5*128*128*2 = 160KB
    const size_t MAT = (size_t)MM * CC * 2;                   // 26,214,400 B each
    unsigned short* qb   = (unsigned short*)(ws + 262144);
    unsigned short* kb   = (unsigned short*)(ws + 262144 + 1 * MAT);
    unsigned short* vb   = (unsigned short*)(ws + 262144 + 2 * MAT);
    unsigned short* gb   = (unsigned short*)(ws + 262144 + 3 * MAT);
    unsigned short* abuf = qb;   // safe alias: attn reads its own Q region before writing O there

    hipLaunchKernelGGL(wtr_kernel, dim3(5), dim3(256), 0, stream, Wq, Wk, Wv, Wg, Wo, WT);
    hipLaunchKernelGGL(proj_kernel, dim3(MM / 64), dim3(256), 0, stream,
                       pair, WT, bq, bk, bv, bg, qb, kb, vb, gb);
    hipLaunchKernelGGL(attn_kernel, dim3(LL, HH), dim3(256), 0, stream, qb, kb, vb, abuf);
    hipLaunchKernelGGL(out_kernel, dim3(MM / 64), dim3(256), 0, stream, abuf, WT, bo, gb, (float*)d_out);
}

// Round 6
// 196.741 us; speedup vs baseline: 1.1478x; 1.1478x over previous
//
#include <hip/hip_runtime.h>
#include <hip/hip_bf16.h>

#define LL 320
#define CC 128
#define HH 4
#define DD 32
#define MM (LL*LL)

typedef float f32x4 __attribute__((ext_vector_type(4)));
typedef short bf16x8 __attribute__((ext_vector_type(8)));

static __device__ __forceinline__ unsigned short f2b(float f) {
    union { float f; unsigned u; } v; v.f = f;
    unsigned r = (v.u + 0x7fffu + ((v.u >> 16) & 1u)) >> 16;
    return (unsigned short)r;
}
static __device__ __forceinline__ float b2f(unsigned short b) {
    union { unsigned u; float f; } v; v.u = ((unsigned)b) << 16;
    return v.f;
}
// packed f32x2 -> bf16x2 (T12 recipe; no builtin on gfx950)
static __device__ __forceinline__ unsigned cvtpk(float a, float b) {
    unsigned r;
    asm("v_cvt_pk_bf16_f32 %0, %1, %2" : "=v"(r) : "v"(a), "v"(b));
    return r;
}

// ---------------------------------------------------------------- weights
// WT[mat][n][k] bf16, mat order: 0=q 1=k 2=v 3=g 4=o. 80 blocks, coalesced dst.
__global__ void wtr_kernel(const float* __restrict__ W0, const float* __restrict__ W1,
                           const float* __restrict__ W2, const float* __restrict__ W3,
                           const float* __restrict__ W4, unsigned short* __restrict__ WT)
{
    int mat = blockIdx.y;
    const float* W = (mat == 0) ? W0 : (mat == 1) ? W1 : (mat == 2) ? W2 : (mat == 3) ? W3 : W4;
    unsigned short* dst = WT + (size_t)mat * CC * CC;
    int n0 = blockIdx.x * 8;
    int t = threadIdx.x;
#pragma unroll
    for (int e = 0; e < 4; ++e) {
        int idx = t + e * 256;           // 0..1023
        int k = idx & 127, nn = idx >> 7;
        dst[(n0 + nn) * CC + k] = f2b(W[k * CC + n0 + nn]);
    }
}

// ---------------------------------------------------------------- QKVG projection
// (byte-identical to round-5 passing version)
__launch_bounds__(256)
__global__ void proj_kernel(const float* __restrict__ X, const unsigned short* __restrict__ WT,
                            const float* __restrict__ bq, const float* __restrict__ bk,
                            const float* __restrict__ bv, const float* __restrict__ bg,
                            unsigned short* __restrict__ qb, unsigned short* __restrict__ kb,
                            unsigned short* __restrict__ vb, unsigned short* __restrict__ gb)
{
    __shared__ unsigned char lds[16384 + 32768];
    const int t = threadIdx.x;
    const int m0 = blockIdx.x * 64;

#pragma unroll
    for (int it = 0; it < 8; ++it) {
        int idx = t + it * 256;              // 0..2047 float4 chunks
        int row = idx >> 5, c4 = idx & 31;
        float4 f = *(const float4*)(X + (size_t)(m0 + row) * CC + c4 * 4);
        unsigned off = (unsigned)(row * 256) + (((unsigned)(c4 * 8)) ^ (((unsigned)(row & 7)) << 4));
        unsigned* p = (unsigned*)(lds + off);
        p[0] = (unsigned)f2b(f.x) | ((unsigned)f2b(f.y) << 16);
        p[1] = (unsigned)f2b(f.z) | ((unsigned)f2b(f.w) << 16);
    }

    const int lane = t & 63, w = t >> 6;
    const int lr = lane & 15, g = lane >> 4;
    const int wr = w >> 1, wc = w & 1;

#pragma unroll
    for (int mat = 0; mat < 4; ++mat) {
        __syncthreads();   // prev compute done (and A visible on iter 0)
        const unsigned short* wsrc = WT + (size_t)mat * CC * CC;
#pragma unroll
        for (int it = 0; it < 8; ++it) {
            int idx = t + it * 256;          // 0..2047 16B chunks (128 rows x 256B)
            int row = idx >> 4, c = idx & 15;
            uint4 d = *(const uint4*)(wsrc + row * CC + c * 8);
            *(uint4*)(lds + 16384 + row * 256u + (((unsigned)(c * 16)) ^ (((unsigned)(row & 7)) << 4))) = d;
        }
        __syncthreads();

        f32x4 acc[2][4] = {};
#pragma unroll
        for (int kk = 0; kk < 4; ++kk) {
            bf16x8 a[2], b[4];
#pragma unroll
            for (int m = 0; m < 2; ++m) {
                int row = wr * 32 + m * 16 + lr;
                a[m] = *(const bf16x8*)(lds + row * 256u +
                        (((unsigned)(kk * 64 + g * 16)) ^ (((unsigned)(row & 7)) << 4)));
            }
#pragma unroll
            for (int n = 0; n < 4; ++n) {
                int row = wc * 64 + n * 16 + lr;
                b[n] = *(const bf16x8*)(lds + 16384 + row * 256u +
                        (((unsigned)(kk * 64 + g * 16)) ^ (((unsigned)(row & 7)) << 4)));
            }
#pragma unroll
            for (int m = 0; m < 2; ++m)
#pragma unroll
                for (int n = 0; n < 4; ++n)
                    acc[m][n] = __builtin_amdgcn_mfma_f32_16x16x32_bf16(a[m], b[n], acc[m][n], 0, 0, 0);
        }

        const float* bias = (mat == 0) ? bq : (mat == 1) ? bk : (mat == 2) ? bv : bg;
        unsigned short* op = (mat == 0) ? qb : (mat == 1) ? kb : (mat == 2) ? vb : gb;
#pragma unroll
        for (int m = 0; m < 2; ++m)
#pragma unroll
            for (int n = 0; n < 4; ++n) {
                int col = wc * 64 + n * 16 + lr;
                float bs = bias[col];
#pragma unroll
                for (int r = 0; r < 4; ++r) {
                    int row = m0 + wr * 32 + m * 16 + g * 4 + r;
                    float v = acc[m][n][r] + bs;
                    if (mat == 3) v = 1.0f / (1.0f + __expf(-v));
                    op[(size_t)row * CC + col] = f2b(v);
                }
            }
    }
}

// ---------------------------------------------------------------- attention
// One block per (i,h). Swapped S^T = mfma(K,Q); in-register P via j-permutation
// (proven round 5). This round: raw v_exp_f32 + v_cvt_pk_bf16_f32 to cut the
// VALU stream (~60 ops/(c,f) saved); structure otherwise identical.
__launch_bounds__(256)
__global__ void attn_kernel(const unsigned short* __restrict__ qb, const unsigned short* __restrict__ kb,
                            const unsigned short* __restrict__ vb, unsigned short* __restrict__ ab)
{
    __shared__ unsigned char lds[20480 + 20480];
    // [0,20480): K [320][32] bf16, row stride 64B, slot ^= (j&3)
    // [20480,40960): VT [32][320] bf16, row stride 640B, slot ^= (d&7)
    const int i = blockIdx.x, h = blockIdx.y;
    const int t = threadIdx.x;
    const size_t base = ((size_t)i * LL) * CC + h * DD;

#pragma unroll
    for (int it = 0; it < 5; ++it) {              // K: 320 rows x 64B
        int idx = t + it * 256;                   // 0..1279
        int j = idx >> 2, ch = idx & 3;
        uint4 d = *(const uint4*)(kb + base + (size_t)j * CC + ch * 8);
        *(uint4*)(lds + j * 64u + ((unsigned)(ch ^ (j & 3)) << 4)) = d;
    }
#pragma unroll
    for (int it = 0; it < 5; ++it) {              // V -> VT transpose
        int idx = t + it * 256;
        int j = idx >> 2, ch = idx & 3;
        uint4 d = *(const uint4*)(vb + base + (size_t)j * CC + ch * 8);
        const unsigned short* ev = (const unsigned short*)&d;
#pragma unroll
        for (int u = 0; u < 8; ++u) {
            int dd = ch * 8 + u;
            unsigned off = 20480u + dd * 640u + (((unsigned)((j >> 3) ^ (dd & 7))) << 4) + (j & 7) * 2;
            *(unsigned short*)(lds + off) = ev[u];
        }
    }

    const int lane = t & 63, w = t >> 6;
    const int lr = lane & 15, g = lane >> 4;

    bf16x8 qf[5];                                  // B=Q fragments, loaded once
#pragma unroll
    for (int f = 0; f < 5; ++f) {
        int q = w * 80 + f * 16 + lr;
        qf[f] = *(const bf16x8*)(qb + base + (size_t)q * CC + g * 8);
    }
    __syncthreads();

    f32x4 acc[5][2] = {};                          // O^T: [qfrag][dfrag]; col=q(lr), row=d
    float lsum[5] = {};
    const float sc = 0.25506601f;                  // log2(e)/sqrt(32)
    f32x4 zero = {0.f, 0.f, 0.f, 0.f};

    for (int c = 0; c < 10; ++c) {                 // j-chunks of 32
        bf16x8 kf[2];
#pragma unroll
        for (int tt = 0; tt < 2; ++tt) {
            int j = c * 32 + tt * 16 + lr;
            kf[tt] = *(const bf16x8*)(lds + j * 64u + ((unsigned)(g ^ (j & 3)) << 4));
        }
        // A=V^T fragments in permuted-j order: elem u=0..3 -> j=c*32+g*4+u,
        // u=4..7 -> j=c*32+16+g*4+(u-4); row d = df*16+lr. Two 8B reads.
        union { bf16x8 v; uint2 u2[2]; } vfrag[2];
#pragma unroll
        for (int df = 0; df < 2; ++df) {
            int dd = df * 16 + lr;
            unsigned rowb = 20480u + dd * 640u + (unsigned)(g & 1) * 8;
            unsigned s0 = (unsigned)((c * 4 + (g >> 1)) ^ (dd & 7));
            unsigned s1 = (unsigned)((c * 4 + (g >> 1) + 2) ^ (dd & 7));
            vfrag[df].u2[0] = *(const uint2*)(lds + rowb + (s0 << 4));
            vfrag[df].u2[1] = *(const uint2*)(lds + rowb + (s1 << 4));
        }
#pragma unroll
        for (int f = 0; f < 5; ++f) {
            f32x4 s0 = __builtin_amdgcn_mfma_f32_16x16x32_bf16(kf[0], qf[f], zero, 0, 0, 0);
            f32x4 s1 = __builtin_amdgcn_mfma_f32_16x16x32_bf16(kf[1], qf[f], zero, 0, 0, 0);
            float p0 = __builtin_amdgcn_exp2f(s0[0] * sc), p1 = __builtin_amdgcn_exp2f(s0[1] * sc);
            float p2 = __builtin_amdgcn_exp2f(s0[2] * sc), p3 = __builtin_amdgcn_exp2f(s0[3] * sc);
            float p4 = __builtin_amdgcn_exp2f(s1[0] * sc), p5 = __builtin_amdgcn_exp2f(s1[1] * sc);
            float p6 = __builtin_amdgcn_exp2f(s1[2] * sc), p7 = __builtin_amdgcn_exp2f(s1[3] * sc);
            lsum[f] += ((p0 + p1) + (p2 + p3)) + ((p4 + p5) + (p6 + p7));
            // B=P fragment in-register; elem order matches vfrag's permuted-j
            union { bf16x8 v; unsigned u[4]; } pf;
            pf.u[0] = cvtpk(p0, p1);
            pf.u[1] = cvtpk(p2, p3);
            pf.u[2] = cvtpk(p4, p5);
            pf.u[3] = cvtpk(p6, p7);
            acc[f][0] = __builtin_amdgcn_mfma_f32_16x16x32_bf16(vfrag[0].v, pf.v, acc[f][0], 0, 0, 0);
            acc[f][1] = __builtin_amdgcn_mfma_f32_16x16x32_bf16(vfrag[1].v, pf.v, acc[f][1], 0, 0, 0);
        }
    }

#pragma unroll
    for (int f = 0; f < 5; ++f) {
        float l = lsum[f];
        l += __shfl_xor(l, 16);
        l += __shfl_xor(l, 32);
        float inv = 1.0f / l;
        int q = w * 80 + f * 16 + lr;
        size_t orow = base + (size_t)q * CC;
#pragma unroll
        for (int df = 0; df < 2; ++df) {
            uint2 ov = {cvtpk(acc[f][df][0] * inv, acc[f][df][1] * inv),
                        cvtpk(acc[f][df][2] * inv, acc[f][df][3] * inv)};
            *(uint2*)(ab + orow + df * 16 + g * 4) = ov;
        }
    }
}

// ---------------------------------------------------------------- O-proj + gate
// (byte-identical to round-5 passing version)
__launch_bounds__(256)
__global__ void out_kernel(const unsigned short* __restrict__ ab, const unsigned short* __restrict__ WT,
                           const float* __restrict__ bo, const unsigned short* __restrict__ gb,
                           float* __restrict__ out)
{
    __shared__ unsigned char lds[16384 + 32768];
    const int t = threadIdx.x;
    const int m0 = blockIdx.x * 64;
#pragma unroll
    for (int it = 0; it < 4; ++it) {               // A: 64 rows x 256B bf16
        int idx = t + it * 256;                    // 0..1023
        int row = idx >> 4, c = idx & 15;
        uint4 d = *(const uint4*)(ab + (size_t)(m0 + row) * CC + c * 8);
        *(uint4*)(lds + row * 256u + (((unsigned)(c * 16)) ^ (((unsigned)(row & 7)) << 4))) = d;
    }
    const unsigned short* wsrc = WT + (size_t)4 * CC * CC;
#pragma unroll
    for (int it = 0; it < 8; ++it) {               // B: 128 rows x 256B
        int idx = t + it * 256;
        int row = idx >> 4, c = idx & 15;
        uint4 d = *(const uint4*)(wsrc + row * CC + c * 8);
        *(uint4*)(lds + 16384 + row * 256u + (((unsigned)(c * 16)) ^ (((unsigned)(row & 7)) << 4))) = d;
    }
    __syncthreads();

    const int lane = t & 63, w = t >> 6;
    const int lr = lane & 15, g = lane >> 4;
    const int wr = w >> 1, wc = w & 1;
    f32x4 acc[2][4] = {};
#pragma unroll
    for (int kk = 0; kk < 4; ++kk) {
        bf16x8 a[2], b[4];
#pragma unroll
        for (int m = 0; m < 2; ++m) {
            int row = wr * 32 + m * 16 + lr;
            a[m] = *(const bf16x8*)(lds + row * 256u +
                    (((unsigned)(kk * 64 + g * 16)) ^ (((unsigned)(row & 7)) << 4)));
        }
#pragma unroll
        for (int n = 0; n < 4; ++n) {
            int row = wc * 64 + n * 16 + lr;
            b[n] = *(const bf16x8*)(lds + 16384 + row * 256u +
                    (((unsigned)(kk * 64 + g * 16)) ^ (((unsigned)(row & 7)) << 4)));
        }
#pragma unroll
        for (int m = 0; m < 2; ++m)
#pragma unroll
            for (int n = 0; n < 4; ++n)
                acc[m][n] = __builtin_amdgcn_mfma_f32_16x16x32_bf16(a[m], b[n], acc[m][n], 0, 0, 0);
    }
#pragma unroll
    for (int m = 0; m < 2; ++m)
#pragma unroll
        for (int n = 0; n < 4; ++n) {
            int col = wc * 64 + n * 16 + lr;
            float bs = bo[col];
#pragma unroll
            for (int r = 0; r < 4; ++r) {
                int row = m0 + wr * 32 + m * 16 + g * 4 + r;
                float y = acc[m][n][r] + bs;
                float gt = b2f(gb[(size_t)row * CC + col]);
                out[(size_t)row * CC + col] = y * gt;
            }
        }
}

// ---------------------------------------------------------------- launch
extern "C" void kernel_launch(void* const* d_in, const int* in_sizes, int n_in,
                              void* d_out, int out_size, void* d_ws, size_t ws_size,
                              hipStream_t stream)
{
    const float* pair = (const float*)d_in[0];
    const float* Wq = (const float*)d_in[1];  const float* bq = (const float*)d_in[2];
    const float* Wk = (const float*)d_in[3];  const float* bk = (const float*)d_in[4];
    const float* Wv = (const float*)d_in[5];  const float* bv = (const float*)d_in[6];
    const float* Wo = (const float*)d_in[7];  const float* bo = (const float*)d_in[8];
    const float* Wg = (const float*)d_in[9];  const float* bg = (const float*)d_in[10];

    char* ws = (char*)d_ws;
    unsigned short* WT = (unsigned short*)ws;                 // 5*128*128*2 = 160KB
    const size_t MAT = (size_t)MM * CC * 2;                   // 26,214,400 B each
    unsigned short* qb   = (unsigned short*)(ws + 262144);
    unsigned short* kb   = (unsigned short*)(ws + 262144 + 1 * MAT);
    unsigned short* vb   = (unsigned short*)(ws + 262144 + 2 * MAT);
    unsigned short* gb   = (unsigned short*)(ws + 262144 + 3 * MAT);
    unsigned short* abuf = qb;   // safe alias: attn reads its own Q region before writing O there

    hipLaunchKernelGGL(wtr_kernel, dim3(16, 5), dim3(256), 0, stream, Wq, Wk, Wv, Wg, Wo, WT);
    hipLaunchKernelGGL(proj_kernel, dim3(MM / 64), dim3(256), 0, stream,
                       pair, WT, bq, bk, bv, bg, qb, kb, vb, gb);
    hipLaunchKernelGGL(attn_kernel, dim3(LL, HH), dim3(256), 0, stream, qb, kb, vb, abuf);
    hipLaunchKernelGGL(out_kernel, dim3(MM / 64), dim3(256), 0, stream, abuf, WT, bo, gb, (float*)d_out);
}